// Round 5
// baseline (100.143 us; speedup 1.0000x reference)
//
#include <hip/hip_runtime.h>
#include <cmath>

#define NB   8
#define NTT  1024
#define MM   64
#define LL   16
#define EE   128

typedef float f32x4 __attribute__((ext_vector_type(4)));
typedef float f32x2 __attribute__((ext_vector_type(2)));

// ---------------- Kernel A: edges -> ws (SoA, f32x4 x3 per task) -------------
__global__ __launch_bounds__(256) void edge_kernel(
    const float* __restrict__ agent,
    const float* __restrict__ lane,
    f32x4* __restrict__ ws0, f32x4* __restrict__ ws1, f32x4* __restrict__ ws2)
{
    const int tid  = threadIdx.x;
    const int nt4  = tid >> 6;                 // 0..3
    const int m    = tid & 63;                 // 0..63
    const int bidx = blockIdx.x * 4 + nt4;     // 0..8191
    const int b    = bidx >> 10;

    const f32x4* ap = reinterpret_cast<const f32x4*>(agent + (size_t)bidx * 8);
    const f32x4 a0 = ap[0];
    const f32x4 a1 = ap[1];
    const float px = a0.x, py = a0.y, ps = a0.w, pc = a1.x;
    const bool z1 = (a0.x == 0.f) & (a0.y == 0.f) & (a0.z == 0.f) & (a0.w == 0.f) &
                    (a1.x == 0.f) & (a1.y == 0.f) & (a1.z == 0.f) & (a1.w == 0.f);
    const float f1 = z1 ? 0.f : 1.f;

    const f32x4* lp = reinterpret_cast<const f32x4*>(lane + ((size_t)b * MM + m) * 64);

    float best = INFINITY;
    f32x4 eMin = (f32x4)(0.f);
    f32x4 eL0  = (f32x4)(0.f);
    f32x4 eL15 = (f32x4)(0.f);
#pragma unroll
    for (int l = 0; l < LL; ++l) {
        const f32x4 lv = lp[l];                   // lx, ly, ls, lc
        const bool z2 = (lv.x == 0.f) & (lv.y == 0.f) & (lv.z == 0.f) & (lv.w == 0.f);
        const float f = z2 ? 0.f : f1;
        const float dxw = px - lv.x;
        const float dyw = py - lv.y;
        f32x4 v;
        v.x = (dxw * lv.w + dyw * lv.z) * 0.1f * f;   // delta_x / 10
        v.y = (dyw * lv.w - dxw * lv.z) * 0.1f * f;   // delta_y / 10
        v.z = (ps * lv.w - pc * lv.z) * f;            // ds
        v.w = (pc * lv.w + ps * lv.z) * f;            // dc
        const float ad = fabsf(v.x);
        if (ad < best) { best = ad; eMin = v; }       // strict < keeps FIRST min
        if (l == 0)      eL0  = v;
        if (l == LL - 1) eL15 = v;
    }
    const int task = bidx * MM + m;   // wave writes 64 consecutive tasks -> 1KB coalesced
    ws0[task] = eMin;
    ws1[task] = eL0;
    ws2[task] = eL15;
}

// ---------------- Kernel B: pure streaming projection ------------------------
__global__ __launch_bounds__(512) void proj_kernel(
    const f32x4* __restrict__ ws0, const f32x4* __restrict__ ws1,
    const f32x4* __restrict__ ws2,
    const float* __restrict__ W, const float* __restrict__ bias,
    float* __restrict__ out)
{
    const int tid = threadIdx.x;
    const int ch  = (tid & 63) * 2;    // 0..126, full-wave channel span
    const int mg  = tid >> 6;          // 0..7, wave-uniform
    const int bidx0 = blockIdx.x * 2;

    float w[2][12];
#pragma unroll
    for (int j = 0; j < 2; ++j) {
        const f32x4* wp = reinterpret_cast<const f32x4*>(W + (size_t)(ch + j) * 12);
        const f32x4 w0 = wp[0], w1 = wp[1], w2 = wp[2];
        w[j][0] = w0.x; w[j][1]  = w0.y; w[j][2]  = w0.z; w[j][3]  = w0.w;
        w[j][4] = w1.x; w[j][5]  = w1.y; w[j][6]  = w1.z; w[j][7]  = w1.w;
        w[j][8] = w2.x; w[j][9]  = w2.y; w[j][10] = w2.z; w[j][11] = w2.w;
    }
    const float bb0 = bias[ch + 0];
    const float bb1 = bias[ch + 1];

#pragma unroll
    for (int nt = 0; nt < 2; ++nt) {
        const int bidx = bidx0 + nt;
        float* outp = out + (size_t)bidx * (MM * EE);
#pragma unroll
        for (int it = 0; it < 8; ++it) {
            const int m = it * 8 + mg;
            const int task = bidx * MM + m;        // wave-uniform -> broadcast load
            const f32x4 p = ws0[task];
            const f32x4 q = ws1[task];
            const f32x4 r = ws2[task];
            float acc0 = bb0, acc1 = bb1;
            acc0 += p.x*w[0][0] + p.y*w[0][1] + p.z*w[0][2]  + p.w*w[0][3]
                  + q.x*w[0][4] + q.y*w[0][5] + q.z*w[0][6]  + q.w*w[0][7]
                  + r.x*w[0][8] + r.y*w[0][9] + r.z*w[0][10] + r.w*w[0][11];
            acc1 += p.x*w[1][0] + p.y*w[1][1] + p.z*w[1][2]  + p.w*w[1][3]
                  + q.x*w[1][4] + q.y*w[1][5] + q.z*w[1][6]  + q.w*w[1][7]
                  + r.x*w[1][8] + r.y*w[1][9] + r.z*w[1][10] + r.w*w[1][11];
            f32x2 res;
            res.x = acc0; res.y = acc1;
            __builtin_nontemporal_store(res,
                reinterpret_cast<f32x2*>(outp + (size_t)m * EE + ch));
        }
    }
}

// ---------------- Fallback: single-kernel (R4) if ws too small ---------------
__global__ __launch_bounds__(512) void a2l_fused(
    const float* __restrict__ agent, const float* __restrict__ lane,
    const float* __restrict__ W, const float* __restrict__ bias,
    float* __restrict__ out)
{
    __shared__ f32x4 sE0[8][MM];
    __shared__ f32x4 sE1[8][MM];
    __shared__ f32x4 sE2[8][MM];
    const int tid = threadIdx.x;
    const int bidx_base = blockIdx.x * 8;
    const int b = bidx_base >> 10;
    {
        const int nt = tid >> 6, m = tid & 63;
        const int bidx = bidx_base + nt;
        const f32x4* ap = reinterpret_cast<const f32x4*>(agent + (size_t)bidx * 8);
        const f32x4 a0 = ap[0], a1 = ap[1];
        const float px = a0.x, py = a0.y, ps = a0.w, pc = a1.x;
        const bool z1 = (a0.x==0.f)&(a0.y==0.f)&(a0.z==0.f)&(a0.w==0.f)&
                        (a1.x==0.f)&(a1.y==0.f)&(a1.z==0.f)&(a1.w==0.f);
        const float f1 = z1 ? 0.f : 1.f;
        const f32x4* lp = reinterpret_cast<const f32x4*>(lane + ((size_t)b*MM + m)*64);
        float best = INFINITY;
        f32x4 eMin=(f32x4)(0.f), eL0=(f32x4)(0.f), eL15=(f32x4)(0.f);
#pragma unroll
        for (int l = 0; l < LL; ++l) {
            const f32x4 lv = lp[l];
            const bool z2 = (lv.x==0.f)&(lv.y==0.f)&(lv.z==0.f)&(lv.w==0.f);
            const float f = z2 ? 0.f : f1;
            const float dxw = px - lv.x, dyw = py - lv.y;
            f32x4 v;
            v.x = (dxw*lv.w + dyw*lv.z)*0.1f*f;
            v.y = (dyw*lv.w - dxw*lv.z)*0.1f*f;
            v.z = (ps*lv.w - pc*lv.z)*f;
            v.w = (pc*lv.w + ps*lv.z)*f;
            const float ad = fabsf(v.x);
            if (ad < best) { best = ad; eMin = v; }
            if (l == 0)      eL0  = v;
            if (l == LL-1)   eL15 = v;
        }
        sE0[nt][m]=eMin; sE1[nt][m]=eL0; sE2[nt][m]=eL15;
    }
    __syncthreads();
    const int ch = (tid & 63)*2, mg = tid >> 6;
    float w[2][12];
#pragma unroll
    for (int j = 0; j < 2; ++j) {
        const f32x4* wp = reinterpret_cast<const f32x4*>(W + (size_t)(ch+j)*12);
        const f32x4 w0=wp[0], w1=wp[1], w2=wp[2];
        w[j][0]=w0.x; w[j][1]=w0.y; w[j][2]=w0.z; w[j][3]=w0.w;
        w[j][4]=w1.x; w[j][5]=w1.y; w[j][6]=w1.z; w[j][7]=w1.w;
        w[j][8]=w2.x; w[j][9]=w2.y; w[j][10]=w2.z; w[j][11]=w2.w;
    }
    const float bb0 = bias[ch], bb1 = bias[ch+1];
    for (int nt = 0; nt < 8; ++nt) {
        float* outp = out + (size_t)(bidx_base + nt)*(MM*EE);
#pragma unroll
        for (int it = 0; it < 8; ++it) {
            const int m = it*8 + mg;
            const f32x4 p=sE0[nt][m], q=sE1[nt][m], r=sE2[nt][m];
            float acc0=bb0, acc1=bb1;
            acc0 += p.x*w[0][0]+p.y*w[0][1]+p.z*w[0][2]+p.w*w[0][3]
                  + q.x*w[0][4]+q.y*w[0][5]+q.z*w[0][6]+q.w*w[0][7]
                  + r.x*w[0][8]+r.y*w[0][9]+r.z*w[0][10]+r.w*w[0][11];
            acc1 += p.x*w[1][0]+p.y*w[1][1]+p.z*w[1][2]+p.w*w[1][3]
                  + q.x*w[1][4]+q.y*w[1][5]+q.z*w[1][6]+q.w*w[1][7]
                  + r.x*w[1][8]+r.y*w[1][9]+r.z*w[1][10]+r.w*w[1][11];
            f32x2 res; res.x=acc0; res.y=acc1;
            *reinterpret_cast<f32x2*>(outp + (size_t)m*EE + ch) = res;
        }
    }
}

extern "C" void kernel_launch(void* const* d_in, const int* in_sizes, int n_in,
                              void* d_out, int out_size, void* d_ws, size_t ws_size,
                              hipStream_t stream) {
    const float* agent = (const float*)d_in[0];
    const float* lane  = (const float*)d_in[1];
    const float* W     = (const float*)d_in[2];
    const float* bias  = (const float*)d_in[3];
    float* out = (float*)d_out;

    const size_t ntask = (size_t)NB * NTT * MM;          // 524288
    const size_t need  = ntask * 16 * 3;                 // 25.2 MB

    if (ws_size >= need) {
        f32x4* ws0 = (f32x4*)d_ws;
        f32x4* ws1 = ws0 + ntask;
        f32x4* ws2 = ws1 + ntask;
        edge_kernel<<<dim3((NB*NTT)/4), dim3(256), 0, stream>>>(agent, lane, ws0, ws1, ws2);
        proj_kernel<<<dim3((NB*NTT)/2), dim3(512), 0, stream>>>(ws0, ws1, ws2, W, bias, out);
    } else {
        a2l_fused<<<dim3((NB*NTT)/8), dim3(512), 0, stream>>>(agent, lane, W, bias, out);
    }
}

// Round 6
// 75.604 us; speedup vs baseline: 1.3246x; 1.3246x over previous
//
#include <hip/hip_runtime.h>
#include <cmath>

#define NB   8
#define NTT  1024
#define MM   64
#define LL   16
#define EE   128
#define NTB  8          // (b,nt) positions per block

typedef float f32x4 __attribute__((ext_vector_type(4)));
typedef float f32x2 __attribute__((ext_vector_type(2)));

__global__ __launch_bounds__(512, 8) void a2l_kernel(
    const float* __restrict__ agent,
    const float* __restrict__ lane,
    const float* __restrict__ W,
    const float* __restrict__ bias,
    float* __restrict__ out,
    int block_offset)
{
    __shared__ f32x4 sE0[NTB][MM];   // argmin point  (4 floats)
    __shared__ f32x4 sE1[NTB][MM];   // l = 0 slice
    __shared__ f32x4 sE2[NTB][MM];   // l = 15 slice

    const int tid       = threadIdx.x;
    const int bidx_base = (blockIdx.x + block_offset) * NTB;  // same b for all 8
    const int b         = bidx_base >> 10;

    // ---- Phase 1: 512 threads = 8 nt × 64 m, one edge each ----
    {
        const int nt = tid >> 6;          // 0..7
        const int m  = tid & 63;          // 0..63
        const int bidx = bidx_base + nt;

        const f32x4* ap = reinterpret_cast<const f32x4*>(agent + (size_t)bidx * 8);
        const f32x4 a0 = ap[0];
        const f32x4 a1 = ap[1];
        const float px = a0.x, py = a0.y, ps = a0.w, pc = a1.x;
        const bool z1 = (a0.x == 0.f) & (a0.y == 0.f) & (a0.z == 0.f) & (a0.w == 0.f) &
                        (a1.x == 0.f) & (a1.y == 0.f) & (a1.z == 0.f) & (a1.w == 0.f);
        const float f1 = z1 ? 0.f : 1.f;

        const f32x4* lp = reinterpret_cast<const f32x4*>(lane + ((size_t)b * MM + m) * 64);

        float best = INFINITY;
        f32x4 eMin = (f32x4)(0.f);
        f32x4 eL0  = (f32x4)(0.f);
        f32x4 eL15 = (f32x4)(0.f);
#pragma unroll
        for (int l = 0; l < LL; ++l) {
            const f32x4 lv = lp[l];                   // lx, ly, ls, lc
            const bool z2 = (lv.x == 0.f) & (lv.y == 0.f) & (lv.z == 0.f) & (lv.w == 0.f);
            const float f = z2 ? 0.f : f1;
            const float dxw = px - lv.x;
            const float dyw = py - lv.y;
            f32x4 v;
            v.x = (dxw * lv.w + dyw * lv.z) * 0.1f * f;   // delta_x / 10
            v.y = (dyw * lv.w - dxw * lv.z) * 0.1f * f;   // delta_y / 10
            v.z = (ps * lv.w - pc * lv.z) * f;            // ds
            v.w = (pc * lv.w + ps * lv.z) * f;            // dc
            const float ad = fabsf(v.x);
            if (ad < best) { best = ad; eMin = v; }       // strict < keeps FIRST min
            if (l == 0)      eL0  = v;
            if (l == LL - 1) eL15 = v;
        }
        sE0[nt][m] = eMin;
        sE1[nt][m] = eL0;
        sE2[nt][m] = eL15;
    }
    __syncthreads();

    // ---- Phase 2: thread owns 2 consecutive channels; 8 nt × 8 m-groups ----
    const int ch = (tid & 63) * 2;      // channel base 0..126 (full-wave span)
    const int mg = tid >> 6;            // 0..7, uniform per wave

    float w[2][12];
#pragma unroll
    for (int j = 0; j < 2; ++j) {
        const f32x4* wp = reinterpret_cast<const f32x4*>(W + (size_t)(ch + j) * 12);
        const f32x4 w0 = wp[0], w1 = wp[1], w2 = wp[2];
        w[j][0] = w0.x; w[j][1]  = w0.y; w[j][2]  = w0.z; w[j][3]  = w0.w;
        w[j][4] = w1.x; w[j][5]  = w1.y; w[j][6]  = w1.z; w[j][7]  = w1.w;
        w[j][8] = w2.x; w[j][9]  = w2.y; w[j][10] = w2.z; w[j][11] = w2.w;
    }
    const float bb0 = bias[ch + 0];
    const float bb1 = bias[ch + 1];

    for (int nt = 0; nt < NTB; ++nt) {
        float* outp = out + (size_t)(bidx_base + nt) * (MM * EE);
#pragma unroll
        for (int it = 0; it < 8; ++it) {
            const int m = it * 8 + mg;
            const f32x4 p = sE0[nt][m];    // full-wave broadcast, conflict-free
            const f32x4 q = sE1[nt][m];
            const f32x4 r = sE2[nt][m];
            float acc0 = bb0, acc1 = bb1;
            acc0 += p.x*w[0][0] + p.y*w[0][1] + p.z*w[0][2]  + p.w*w[0][3]
                  + q.x*w[0][4] + q.y*w[0][5] + q.z*w[0][6]  + q.w*w[0][7]
                  + r.x*w[0][8] + r.y*w[0][9] + r.z*w[0][10] + r.w*w[0][11];
            acc1 += p.x*w[1][0] + p.y*w[1][1] + p.z*w[1][2]  + p.w*w[1][3]
                  + q.x*w[1][4] + q.y*w[1][5] + q.z*w[1][6]  + q.w*w[1][7]
                  + r.x*w[1][8] + r.y*w[1][9] + r.z*w[1][10] + r.w*w[1][11];
            f32x2 res;
            res.x = acc0; res.y = acc1;
            *reinterpret_cast<f32x2*>(outp + (size_t)m * EE + ch) = res;
        }
    }
}

extern "C" void kernel_launch(void* const* d_in, const int* in_sizes, int n_in,
                              void* d_out, int out_size, void* d_ws, size_t ws_size,
                              hipStream_t stream) {
    const float* agent = (const float*)d_in[0];
    const float* lane  = (const float*)d_in[1];
    const float* W     = (const float*)d_in[2];
    const float* bias  = (const float*)d_in[3];
    float* out = (float*)d_out;

    const int total_blocks = (NB * NTT) / NTB;   // 1024
    const int half = total_blocks / 2;           // 512
    // PROBE: identical total work, split into two sequential dispatches to
    // measure per-dispatch overhead. Work, bytes, instruction stream unchanged.
    a2l_kernel<<<dim3(half), dim3(512), 0, stream>>>(agent, lane, W, bias, out, 0);
    a2l_kernel<<<dim3(half), dim3(512), 0, stream>>>(agent, lane, W, bias, out, half);
}

// Round 7
// 59.624 us; speedup vs baseline: 1.6796x; 1.2680x over previous
//
#include <hip/hip_runtime.h>
#include <cmath>

#define NB   8
#define NTT  1024
#define MM   64
#define LL   16
#define EE   128
#define NTB  8          // (b,nt) positions per block == waves per block

typedef float f32x4 __attribute__((ext_vector_type(4)));

__global__ __launch_bounds__(512, 6) void a2l_kernel(
    const float* __restrict__ agent,
    const float* __restrict__ lane,
    const float* __restrict__ W,
    const float* __restrict__ bias,
    float* __restrict__ out)
{
    __shared__ f32x4 sE0[NTB][MM];   // argmin point
    __shared__ f32x4 sE1[NTB][MM];   // l = 0 slice
    __shared__ f32x4 sE2[NTB][MM];   // l = 15 slice

    const int tid       = threadIdx.x;
    const int wv        = tid >> 6;          // wave id == nt, 0..7
    const int ln        = tid & 63;          // lane
    const int bidx_base = blockIdx.x * NTB;  // 8-aligned => same b for all 8
    const int b         = bidx_base >> 10;
    const int bidx      = bidx_base + wv;

    // ---- weight/bias register loads (4 consecutive channels per thread) ----
    const int ch = (ln & 31) * 4;            // 0..124
    float w[4][12];
#pragma unroll
    for (int j = 0; j < 4; ++j) {
        const f32x4* wp = reinterpret_cast<const f32x4*>(W + (size_t)(ch + j) * 12);
        const f32x4 w0 = wp[0], w1 = wp[1], w2 = wp[2];
        w[j][0] = w0.x; w[j][1]  = w0.y; w[j][2]  = w0.z; w[j][3]  = w0.w;
        w[j][4] = w1.x; w[j][5]  = w1.y; w[j][6]  = w1.z; w[j][7]  = w1.w;
        w[j][8] = w2.x; w[j][9]  = w2.y; w[j][10] = w2.z; w[j][11] = w2.w;
    }
    const f32x4 bb = *reinterpret_cast<const f32x4*>(bias + ch);

    // ---- Phase 1: each lane computes the edge for (bidx, m = lane) ----
    {
        const int m = ln;
        const f32x4* ap = reinterpret_cast<const f32x4*>(agent + (size_t)bidx * 8);
        const f32x4 a0 = ap[0];
        const f32x4 a1 = ap[1];
        const float px = a0.x, py = a0.y, ps = a0.w, pc = a1.x;
        const bool z1 = (a0.x == 0.f) & (a0.y == 0.f) & (a0.z == 0.f) & (a0.w == 0.f) &
                        (a1.x == 0.f) & (a1.y == 0.f) & (a1.z == 0.f) & (a1.w == 0.f);
        const float f1 = z1 ? 0.f : 1.f;

        const f32x4* lp = reinterpret_cast<const f32x4*>(lane + ((size_t)b * MM + m) * 64);

        float best = INFINITY;
        f32x4 eMin = (f32x4)(0.f);
        f32x4 eL0  = (f32x4)(0.f);
        f32x4 eL15 = (f32x4)(0.f);
#pragma unroll
        for (int l = 0; l < LL; ++l) {
            const f32x4 lv = lp[l];                   // lx, ly, ls, lc
            const bool z2 = (lv.x == 0.f) & (lv.y == 0.f) & (lv.z == 0.f) & (lv.w == 0.f);
            const float f = z2 ? 0.f : f1;
            const float dxw = px - lv.x;
            const float dyw = py - lv.y;
            f32x4 v;
            v.x = (dxw * lv.w + dyw * lv.z) * 0.1f * f;   // delta_x / 10
            v.y = (dyw * lv.w - dxw * lv.z) * 0.1f * f;   // delta_y / 10
            v.z = (ps * lv.w - pc * lv.z) * f;            // ds
            v.w = (pc * lv.w + ps * lv.z) * f;            // dc
            const float ad = fabsf(v.x);
            if (ad < best) { best = ad; eMin = v; }       // strict < keeps FIRST min
            if (l == 0)      eL0  = v;
            if (l == LL - 1) eL15 = v;
        }
        sE0[wv][m] = eMin;
        sE1[wv][m] = eL0;
        sE2[wv][m] = eL15;
    }
    // NO __syncthreads(): wave wv wrote sE*[wv][*] and is the only reader of it.
    // Same-wave LDS write->read ordering is enforced via lgkmcnt by the compiler.

    // ---- Phase 2: wave wv streams its contiguous 32KB region linearly ----
    // iteration it: lanes 0..31 -> row m=2*it (channels ch..ch+3),
    //               lanes 32..63 -> row m=2*it+1  => 1KB contiguous per store instr,
    // successive its advance linearly through [bidx*32KB, +32KB).
    const int mh = ln >> 5;                  // 0 or 1
    float* outp = out + (size_t)bidx * (MM * EE);

#pragma unroll 4
    for (int it = 0; it < 32; ++it) {
        const int m = it * 2 + mh;
        const f32x4 p = sE0[wv][m];
        const f32x4 q = sE1[wv][m];
        const f32x4 r = sE2[wv][m];
        f32x4 res;
        res.x = bb.x + p.x*w[0][0] + p.y*w[0][1] + p.z*w[0][2]  + p.w*w[0][3]
                     + q.x*w[0][4] + q.y*w[0][5] + q.z*w[0][6]  + q.w*w[0][7]
                     + r.x*w[0][8] + r.y*w[0][9] + r.z*w[0][10] + r.w*w[0][11];
        res.y = bb.y + p.x*w[1][0] + p.y*w[1][1] + p.z*w[1][2]  + p.w*w[1][3]
                     + q.x*w[1][4] + q.y*w[1][5] + q.z*w[1][6]  + q.w*w[1][7]
                     + r.x*w[1][8] + r.y*w[1][9] + r.z*w[1][10] + r.w*w[1][11];
        res.z = bb.z + p.x*w[2][0] + p.y*w[2][1] + p.z*w[2][2]  + p.w*w[2][3]
                     + q.x*w[2][4] + q.y*w[2][5] + q.z*w[2][6]  + q.w*w[2][7]
                     + r.x*w[2][8] + r.y*w[2][9] + r.z*w[2][10] + r.w*w[2][11];
        res.w = bb.w + p.x*w[3][0] + p.y*w[3][1] + p.z*w[3][2]  + p.w*w[3][3]
                     + q.x*w[3][4] + q.y*w[3][5] + q.z*w[3][6]  + q.w*w[3][7]
                     + r.x*w[3][8] + r.y*w[3][9] + r.z*w[3][10] + r.w*w[3][11];
        __builtin_nontemporal_store(res,
            reinterpret_cast<f32x4*>(outp + (size_t)m * EE + ch));
    }
}

extern "C" void kernel_launch(void* const* d_in, const int* in_sizes, int n_in,
                              void* d_out, int out_size, void* d_ws, size_t ws_size,
                              hipStream_t stream) {
    const float* agent = (const float*)d_in[0];
    const float* lane  = (const float*)d_in[1];
    const float* W     = (const float*)d_in[2];
    const float* bias  = (const float*)d_in[3];
    float* out = (float*)d_out;

    dim3 grid((NB * NTT) / NTB);   // 1024 blocks
    dim3 block(512);
    a2l_kernel<<<grid, block, 0, stream>>>(agent, lane, W, bias, out);
}

// Round 8
// 56.910 us; speedup vs baseline: 1.7597x; 1.0477x over previous
//
#include <hip/hip_runtime.h>
#include <cmath>

#define NB   8
#define NTT  1024
#define MM   64
#define LL   16
#define EE   128
#define NTB  8          // (b,nt) positions per block == waves per block

typedef float f32x4 __attribute__((ext_vector_type(4)));

__global__ __launch_bounds__(512, 6) void a2l_kernel(
    const float* __restrict__ agent,
    const float* __restrict__ lane,
    const float* __restrict__ W,
    const float* __restrict__ bias,
    float* __restrict__ out)
{
    __shared__ f32x4 sE0[NTB][MM];   // argmin point
    __shared__ f32x4 sE1[NTB][MM];   // l = 0 slice
    __shared__ f32x4 sE2[NTB][MM];   // l = 15 slice

    const int tid       = threadIdx.x;
    const int wv        = tid >> 6;          // wave id == nt, 0..7
    const int ln        = tid & 63;          // lane
    const int bidx_base = blockIdx.x * NTB;  // 8-aligned => same b for all 8
    const int b         = bidx_base >> 10;
    const int bidx      = bidx_base + wv;

    // ---- weight/bias register loads (4 consecutive channels per thread) ----
    const int ch = (ln & 31) * 4;            // 0..124
    float w[4][12];
#pragma unroll
    for (int j = 0; j < 4; ++j) {
        const f32x4* wp = reinterpret_cast<const f32x4*>(W + (size_t)(ch + j) * 12);
        const f32x4 w0 = wp[0], w1 = wp[1], w2 = wp[2];
        w[j][0] = w0.x; w[j][1]  = w0.y; w[j][2]  = w0.z; w[j][3]  = w0.w;
        w[j][4] = w1.x; w[j][5]  = w1.y; w[j][6]  = w1.z; w[j][7]  = w1.w;
        w[j][8] = w2.x; w[j][9]  = w2.y; w[j][10] = w2.z; w[j][11] = w2.w;
    }
    const f32x4 bb = *reinterpret_cast<const f32x4*>(bias + ch);

    // ---- Phase 1: each lane computes the edge for (bidx, m = lane) ----
    {
        const int m = ln;
        const f32x4* ap = reinterpret_cast<const f32x4*>(agent + (size_t)bidx * 8);
        const f32x4 a0 = ap[0];
        const f32x4 a1 = ap[1];
        const float px = a0.x, py = a0.y, ps = a0.w, pc = a1.x;
        const bool z1 = (a0.x == 0.f) & (a0.y == 0.f) & (a0.z == 0.f) & (a0.w == 0.f) &
                        (a1.x == 0.f) & (a1.y == 0.f) & (a1.z == 0.f) & (a1.w == 0.f);
        const float f1 = z1 ? 0.f : 1.f;

        const f32x4* lp = reinterpret_cast<const f32x4*>(lane + ((size_t)b * MM + m) * 64);

        float best = INFINITY;
        f32x4 eMin = (f32x4)(0.f);
        f32x4 eL0  = (f32x4)(0.f);
        f32x4 eL15 = (f32x4)(0.f);
#pragma unroll
        for (int l = 0; l < LL; ++l) {
            const f32x4 lv = lp[l];                   // lx, ly, ls, lc
            const bool z2 = (lv.x == 0.f) & (lv.y == 0.f) & (lv.z == 0.f) & (lv.w == 0.f);
            const float f = z2 ? 0.f : f1;
            const float dxw = px - lv.x;
            const float dyw = py - lv.y;
            f32x4 v;
            v.x = (dxw * lv.w + dyw * lv.z) * 0.1f * f;   // delta_x / 10
            v.y = (dyw * lv.w - dxw * lv.z) * 0.1f * f;   // delta_y / 10
            v.z = (ps * lv.w - pc * lv.z) * f;            // ds
            v.w = (pc * lv.w + ps * lv.z) * f;            // dc
            const float ad = fabsf(v.x);
            if (ad < best) { best = ad; eMin = v; }       // strict < keeps FIRST min
            if (l == 0)      eL0  = v;
            if (l == LL - 1) eL15 = v;
        }
        sE0[wv][m] = eMin;
        sE1[wv][m] = eL0;
        sE2[wv][m] = eL15;
    }
    // NO __syncthreads(): wave wv wrote sE*[wv][*] and is the only reader of it.

    // ---- Phase 2: wave wv streams its contiguous 32KB region linearly ----
    const int mh = ln >> 5;                  // 0 or 1
    float* outp = out + (size_t)bidx * (MM * EE);

#pragma unroll 4
    for (int it = 0; it < 32; ++it) {
        const int m = it * 2 + mh;
        const f32x4 p = sE0[wv][m];
        const f32x4 q = sE1[wv][m];
        const f32x4 r = sE2[wv][m];
        f32x4 res;
        res.x = bb.x + p.x*w[0][0] + p.y*w[0][1] + p.z*w[0][2]  + p.w*w[0][3]
                     + q.x*w[0][4] + q.y*w[0][5] + q.z*w[0][6]  + q.w*w[0][7]
                     + r.x*w[0][8] + r.y*w[0][9] + r.z*w[0][10] + r.w*w[0][11];
        res.y = bb.y + p.x*w[1][0] + p.y*w[1][1] + p.z*w[1][2]  + p.w*w[1][3]
                     + q.x*w[1][4] + q.y*w[1][5] + q.z*w[1][6]  + q.w*w[1][7]
                     + r.x*w[1][8] + r.y*w[1][9] + r.z*w[1][10] + r.w*w[1][11];
        res.z = bb.z + p.x*w[2][0] + p.y*w[2][1] + p.z*w[2][2]  + p.w*w[2][3]
                     + q.x*w[2][4] + q.y*w[2][5] + q.z*w[2][6]  + q.w*w[2][7]
                     + r.x*w[2][8] + r.y*w[2][9] + r.z*w[2][10] + r.w*w[2][11];
        res.w = bb.w + p.x*w[3][0] + p.y*w[3][1] + p.z*w[3][2]  + p.w*w[3][3]
                     + q.x*w[3][4] + q.y*w[3][5] + q.z*w[3][6]  + q.w*w[3][7]
                     + r.x*w[3][8] + r.y*w[3][9] + r.z*w[3][10] + r.w*w[3][11];
        // A/B vs R7: plain store (let L3 absorb the write-back) instead of NT
        *reinterpret_cast<f32x4*>(outp + (size_t)m * EE + ch) = res;
    }
}

extern "C" void kernel_launch(void* const* d_in, const int* in_sizes, int n_in,
                              void* d_out, int out_size, void* d_ws, size_t ws_size,
                              hipStream_t stream) {
    const float* agent = (const float*)d_in[0];
    const float* lane  = (const float*)d_in[1];
    const float* W     = (const float*)d_in[2];
    const float* bias  = (const float*)d_in[3];
    float* out = (float*)d_out;

    dim3 grid((NB * NTT) / NTB);   // 1024 blocks
    dim3 block(512);
    a2l_kernel<<<grid, block, 0, stream>>>(agent, lane, W, bias, out);
}